// Round 5
// baseline (648.688 us; speedup 1.0000x reference)
//
#include <hip/hip_runtime.h>
#include <hip/hip_bf16.h>
#include <math.h>

// GCN stack: 3x [GCNConv + ReLU] + MLP head (64->32 relu ->40) + log_softmax.
// R5: gather restructured to 8 nodes/wave x 8 lanes/node — removes the
// shfl-fold and index-broadcast per-node overhead that R4's post-mortem
// identified (halving line traffic in R4 only gave 17%, so the gather was
// wave-overhead-bound, not line-bound). Line traffic unchanged.
// out[d] = relu(dinv[d] * (h'[d] + sum_{s in N_in(d)} h'[s]) + b),
// h' = dinv * (x @ W), hprime stored bf16 (128B rows).

#define DIMF 64

// ---------------- CSR build ----------------

__global__ __launch_bounds__(256) void zero_counts(int* cnt, int n) {
    int i = blockIdx.x * 256 + threadIdx.x;
    if (i < n) cnt[i] = 0;
}

__global__ __launch_bounds__(256) void hist_dst(const int* __restrict__ dst,
                                                int* __restrict__ cnt, int E) {
    int e = blockIdx.x * 256 + threadIdx.x;
    if (e < E) atomicAdd(&cnt[dst[e]], 1);
}

// Per-block exclusive scan of cnt -> row_start (partial), block totals -> bsum.
__global__ __launch_bounds__(256) void scan_block(const int* __restrict__ cnt,
                                                  int* __restrict__ row_start,
                                                  int* __restrict__ bsum, int n) {
    __shared__ int s[256];
    int t = threadIdx.x;
    int i = blockIdx.x * 256 + t;
    int c = (i < n) ? cnt[i] : 0;
    s[t] = c;
    __syncthreads();
    for (int off = 1; off < 256; off <<= 1) {
        int v = (t >= off) ? s[t - off] : 0;
        __syncthreads();
        s[t] += v;
        __syncthreads();
    }
    int incl = s[t];
    if (i < n) row_start[i] = incl - c;
    if (t == 255) bsum[blockIdx.x] = incl;
}

// Single-block exclusive scan of block sums (nb <= 512).
__global__ __launch_bounds__(512) void scan_bsum(int* __restrict__ bsum, int nb) {
    __shared__ int s[512];
    int t = threadIdx.x;
    int c = (t < nb) ? bsum[t] : 0;
    s[t] = c;
    __syncthreads();
    for (int off = 1; off < 512; off <<= 1) {
        int v = (t >= off) ? s[t - off] : 0;
        __syncthreads();
        s[t] += v;
        __syncthreads();
    }
    if (t < nb) bsum[t] = s[t] - c;   // exclusive
}

// row_start += bsum[blk]; cursor (=cnt reused) = row_start; dinv = rsqrt(deg+1).
__global__ __launch_bounds__(256) void scan_finalize(
    int* __restrict__ cnt, int* __restrict__ row_start,
    const int* __restrict__ bsum, float* __restrict__ dinv, int n, int E) {
    int i = blockIdx.x * 256 + threadIdx.x;
    if (i < n) {
        int c = cnt[i];
        int rsf = row_start[i] + bsum[i >> 8];
        row_start[i] = rsf;
        cnt[i] = rsf;                        // becomes the placement cursor
        dinv[i] = rsqrtf((float)c + 1.0f);   // +1 self loop
    }
    if (i == 0) row_start[n] = E;
}

__global__ __launch_bounds__(256) void place_edges(
    const int* __restrict__ src, const int* __restrict__ dst,
    int* __restrict__ cursor, int* __restrict__ csr_src, int E) {
    int e = blockIdx.x * 256 + threadIdx.x;
    if (e < E) {
        int p = atomicAdd(&cursor[dst[e]], 1);
        csr_src[p] = src[e];
    }
}

// ---------------- per-layer kernels ----------------

// hprime(bf16) = dinv[row] * (xin @ W).  32 rows x 64 cols per block.
__global__ __launch_bounds__(256) void gemm_scale(
    const float* __restrict__ xin, const float* __restrict__ W,
    const float* __restrict__ dinv, __hip_bfloat16* __restrict__ hprime, int n)
{
    __shared__ float Ws[64 * 64];        // 16 KB
    __shared__ float Xs[32][65];         // 8.3 KB, +1 pad
    int t = threadIdx.x;
    for (int i = t; i < 64 * 64; i += 256) Ws[i] = W[i];
    int row0 = blockIdx.x * 32;
    for (int i = t; i < 32 * 64; i += 256) {
        int r = i >> 6, c = i & 63;
        int gr = row0 + r;
        Xs[r][c] = (gr < n) ? xin[(size_t)gr * DIMF + c] : 0.0f;
    }
    __syncthreads();
    int col = t & 63;
    int rbase = (t >> 6) * 8;            // 0,8,16,24
    float av[8];
#pragma unroll
    for (int rr = 0; rr < 8; rr++) av[rr] = 0.0f;
    for (int k = 0; k < 64; k++) {
        float w = Ws[k * 64 + col];      // lanes -> consecutive banks
#pragma unroll
        for (int rr = 0; rr < 8; rr++)   // Xs read is wave-broadcast
            av[rr] = fmaf(Xs[rbase + rr][k], w, av[rr]);
    }
#pragma unroll
    for (int rr = 0; rr < 8; rr++) {
        int gr = row0 + rbase + rr;
        if (gr < n)
            hprime[(size_t)gr * DIMF + col] = __float2bfloat16(av[rr] * dinv[gr]);
    }
}

// 8 nodes per wave, 8 lanes per node: slot = lane>>3 (node), oct = lane&7
// (feature octet). Each lane privately accumulates its 8 features over the
// node's edge list: 16B uint4 bf16 loads, f32 accumulate, no shfl, no fold.
// Index load prefetched one edge ahead; 8 lanes/node read csr_src at the
// same address (HW broadcast).
__global__ __launch_bounds__(256) void gather_relu(
    const unsigned int* __restrict__ hprime,  // bf16x2 packed, 32 uints/row
    const int* __restrict__ row_start, const int* __restrict__ csr_src,
    const float* __restrict__ dinv, const float* __restrict__ b,
    float* __restrict__ xout, int n)
{
    int wave = threadIdx.x >> 6;
    int lane = threadIdx.x & 63;
    int slot = lane >> 3;            // node slot 0..7
    int uoff = (lane & 7) << 2;      // uint index within 32-uint row
    int node = (blockIdx.x * 4 + wave) * 8 + slot;
    if (node >= n) return;

    int rs = row_start[node];
    int re = row_start[node + 1];
    int deg = re - rs;

    float acc[8];
#pragma unroll
    for (int i = 0; i < 8; i++) acc[i] = 0.0f;

#define ADDROW(v)                                                          \
    {                                                                      \
        acc[0] += __uint_as_float((v).x << 16);                            \
        acc[1] += __uint_as_float((v).x & 0xffff0000u);                    \
        acc[2] += __uint_as_float((v).y << 16);                            \
        acc[3] += __uint_as_float((v).y & 0xffff0000u);                    \
        acc[4] += __uint_as_float((v).z << 16);                            \
        acc[5] += __uint_as_float((v).z & 0xffff0000u);                    \
        acc[6] += __uint_as_float((v).w << 16);                            \
        acc[7] += __uint_as_float((v).w & 0xffff0000u);                    \
    }

    {   // self loop
        uint4 v = *(const uint4*)(hprime + (size_t)node * 32 + uoff);
        ADDROW(v);
    }
    if (deg > 0) {
        int idx = csr_src[rs];
        for (int k = 0; k < deg; k++) {
            int nxt = (k + 1 < deg) ? csr_src[rs + k + 1] : 0;  // prefetch
            uint4 v = *(const uint4*)(hprime + (size_t)idx * 32 + uoff);
            ADDROW(v);
            idx = nxt;
        }
    }
#undef ADDROW

    int f8 = uoff << 1;              // feature base = (lane&7)*8
    float dv = dinv[node];
    float4 o0, o1;
    o0.x = fmaxf(fmaf(dv, acc[0], b[f8 + 0]), 0.0f);
    o0.y = fmaxf(fmaf(dv, acc[1], b[f8 + 1]), 0.0f);
    o0.z = fmaxf(fmaf(dv, acc[2], b[f8 + 2]), 0.0f);
    o0.w = fmaxf(fmaf(dv, acc[3], b[f8 + 3]), 0.0f);
    o1.x = fmaxf(fmaf(dv, acc[4], b[f8 + 4]), 0.0f);
    o1.y = fmaxf(fmaf(dv, acc[5], b[f8 + 5]), 0.0f);
    o1.z = fmaxf(fmaf(dv, acc[6], b[f8 + 6]), 0.0f);
    o1.w = fmaxf(fmaf(dv, acc[7], b[f8 + 7]), 0.0f);
    float* op = xout + (size_t)node * DIMF + f8;
    *(float4*)(op)     = o0;
    *(float4*)(op + 4) = o1;
}

// MLP head + log_softmax. 128 threads = 128 nodes per block.
__global__ __launch_bounds__(128) void head_kernel(
    const float* __restrict__ x, const float* __restrict__ Wp1,
    const float* __restrict__ bp1, const float* __restrict__ Wp2,
    const float* __restrict__ bp2, float* __restrict__ out, int n)
{
    __shared__ float Xs[128][65];        // 33.3 KB
    __shared__ float W1s[64 * 32];       // 8 KB
    __shared__ float W2s[32 * 40];       // 5 KB
    __shared__ float b1s[32], b2s[40];
    int t = threadIdx.x;
    for (int i = t; i < 64 * 32; i += 128) W1s[i] = Wp1[i];
    for (int i = t; i < 32 * 40; i += 128) W2s[i] = Wp2[i];
    if (t < 32) b1s[t] = bp1[t];
    if (t < 40) b2s[t] = bp2[t];
    int row0 = blockIdx.x * 128;
    for (int i = t; i < 128 * 64; i += 128) {
        int r = i >> 6, c = i & 63;
        int gr = row0 + r;
        Xs[r][c] = (gr < n) ? x[(size_t)gr * DIMF + c] : 0.0f;
    }
    __syncthreads();
    int node = row0 + t;
    if (node >= n) return;

    float h[32];
#pragma unroll
    for (int j = 0; j < 32; j++) h[j] = b1s[j];
    for (int k = 0; k < 64; k++) {
        float xv = Xs[t][k];
#pragma unroll
        for (int j = 0; j < 32; j++) h[j] = fmaf(xv, W1s[k * 32 + j], h[j]);
    }
#pragma unroll
    for (int j = 0; j < 32; j++) h[j] = h[j] > 0.0f ? h[j] : 0.0f;

    float o[40];
#pragma unroll
    for (int j = 0; j < 40; j++) o[j] = b2s[j];
    for (int k = 0; k < 32; k++) {
        float hv = h[k];
#pragma unroll
        for (int j = 0; j < 40; j++) o[j] = fmaf(hv, W2s[k * 40 + j], o[j]);
    }
    float m = o[0];
#pragma unroll
    for (int j = 1; j < 40; j++) m = fmaxf(m, o[j]);
    float sum = 0.0f;
#pragma unroll
    for (int j = 0; j < 40; j++) sum += expf(o[j] - m);
    float lse = logf(sum) + m;
    float* op = out + (size_t)node * 40;
#pragma unroll
    for (int j = 0; j < 40; j++) op[j] = o[j] - lse;
}

extern "C" void kernel_launch(void* const* d_in, const int* in_sizes, int n_in,
                              void* d_out, int out_size, void* d_ws, size_t ws_size,
                              hipStream_t stream)
{
    const float* x  = (const float*)d_in[0];
    const int*   ei = (const int*)d_in[1];
    const int E = in_sizes[1] / 2;
    const int n = in_sizes[0] / DIMF;
    const int* src = ei;
    const int* dst = ei + E;
    const float* W[3] = {(const float*)d_in[3], (const float*)d_in[5], (const float*)d_in[7]};
    const float* b[3] = {(const float*)d_in[4], (const float*)d_in[6], (const float*)d_in[8]};
    const float* Wp1 = (const float*)d_in[9];
    const float* bp1 = (const float*)d_in[10];
    const float* Wp2 = (const float*)d_in[11];
    const float* bp2 = (const float*)d_in[12];
    float* out = (float*)d_out;

    const int nb = (n + 255) / 256;      // <= 512 for n <= 131072

    // Workspace layout: cnt[n] | row_start[n+1] | bsum[512] | csr_src[E] |
    //                   dinv[n] | hprime[n*64 bf16] | xbuf[n*64 f32]
    char* p = (char*)d_ws;
    int* cnt       = (int*)p;                 p += (size_t)n * 4;
    int* row_start = (int*)p;                 p += (size_t)(n + 1) * 4;
    p = (char*)(((size_t)p + 15) & ~(size_t)15);
    int* bsum      = (int*)p;                 p += 512 * 4;
    int* csr_src   = (int*)p;                 p += (size_t)E * 4;
    p = (char*)(((size_t)p + 15) & ~(size_t)15);
    float* dinv    = (float*)p;               p += (size_t)n * 4;
    p = (char*)(((size_t)p + 15) & ~(size_t)15);
    __hip_bfloat16* hprime = (__hip_bfloat16*)p;  p += (size_t)n * DIMF * 2;
    p = (char*)(((size_t)p + 15) & ~(size_t)15);
    float* xbuf    = (float*)p;

    // --- CSR build (index-space atomics only) ---
    hipLaunchKernelGGL(zero_counts,  dim3(nb), dim3(256), 0, stream, cnt, n);
    hipLaunchKernelGGL(hist_dst,     dim3((E + 255) / 256), dim3(256), 0, stream, dst, cnt, E);
    hipLaunchKernelGGL(scan_block,   dim3(nb), dim3(256), 0, stream, cnt, row_start, bsum, n);
    hipLaunchKernelGGL(scan_bsum,    dim3(1), dim3(512), 0, stream, bsum, nb);
    hipLaunchKernelGGL(scan_finalize,dim3(nb), dim3(256), 0, stream, cnt, row_start, bsum, dinv, n, E);
    hipLaunchKernelGGL(place_edges,  dim3((E + 255) / 256), dim3(256), 0, stream,
                       src, dst, cnt, csr_src, E);

    // --- 3 GCN layers ---
    const float* xin = x;
    for (int l = 0; l < 3; l++) {
        hipLaunchKernelGGL(gemm_scale, dim3((n + 31) / 32), dim3(256), 0, stream,
                           xin, W[l], dinv, hprime, n);
        hipLaunchKernelGGL(gather_relu, dim3((n + 31) / 32), dim3(256), 0, stream,
                           (const unsigned int*)hprime, row_start, csr_src, dinv,
                           b[l], xbuf, n);
        xin = xbuf;
    }

    // --- head ---
    hipLaunchKernelGGL(head_kernel, dim3((n + 127) / 128), dim3(128), 0, stream,
                       xbuf, Wp1, bp1, Wp2, bp2, out, n);
}